// Round 5
// baseline (444.530 us; speedup 1.0000x reference)
//
#include <hip/hip_runtime.h>
#include <stdint.h>

#define BATCH_N   131072
#define HID       256
#define SPIKE_DIM 128
#define COORD_DIM 64
#define IN_DIM    192
#define STEPS     25
#define BLOCK     512

typedef float f4  __attribute__((ext_vector_type(4)));
typedef short bf8 __attribute__((ext_vector_type(8)));
typedef unsigned short us4 __attribute__((ext_vector_type(4)));

// ws layout:
//   W0b  [256][192] bf16   at byte 0        (49152 ushorts = 96 KB)
//   W1T  [256][256] fp32   at float 24576   (65536 floats)
//   WoT  [256][64]  fp32   at float 90112   (16384 floats)
//   scalars           at float 106496: [0]=max(b1,0), [1]=max(W1+,0)
#define W1T_OFF  24576
#define WOT_OFF  90112
#define SCAL_OFF 106496

static __device__ __forceinline__ unsigned short f2bf(float f) {
  union { float f; unsigned u; } v; v.f = f;
  unsigned r = v.u + 0x7FFF + ((v.u >> 16) & 1);   // RNE
  return (unsigned short)(r >> 16);
}

__global__ __launch_bounds__(256)
void prep_kernel(const float* __restrict__ W0,
                 const float* __restrict__ W1,
                 const float* __restrict__ Wout,
                 const float* __restrict__ b1,
                 float* __restrict__ ws) {
  // Screen scalars via parallel wave-reduce + atomicMax on float bits
  // (values >=0 after fmaxf(.,0), so uint order == float order). ws[SCAL..]
  // is zeroed by hipMemsetAsync before launch (R1 lesson: no serial
  // reduction chains; R3/R4: keep prep off the critical path).
  const int t = threadIdx.x, b = blockIdx.x;
  if (b == 512) {
    unsigned u = __float_as_uint(fmaxf(b1[t], 0.f));
    #pragma unroll
    for (int o = 1; o < 64; o <<= 1) {
      unsigned v = __shfl_xor(u, o);
      u = v > u ? v : u;
    }
    if ((t & 63) == 0) atomicMax((unsigned*)(ws + SCAL_OFF), u);
    return;
  }
  int idx = b * 256 + t;
  if (idx < HID*IN_DIM) {               // W0b elementwise (row-major, k-contig)
    ((unsigned short*)ws)[idx] = f2bf(W0[idx]);
  }
  int i1 = idx - HID*IN_DIM;            // W1T[j][i] = W1[i][j]
  if (i1 >= 0 && i1 < HID*HID) {
    int j = i1 >> 8, i = i1 & 255;
    ws[W1T_OFF + i1] = W1[i*HID + j];
  }
  int i2 = idx - (HID*IN_DIM + HID*HID);// WoT[k][c] = Wout[128+c][k]
  if (i2 >= 0 && i2 < HID*COORD_DIM) {
    int k = i2 >> 6, c = i2 & 63;
    ws[WOT_OFF + i2] = Wout[(SPIKE_DIM + c)*HID + k];
  }
  if (b < 64) {                         // W1 max: 64 blocks cover 16384 f4
    f4 v = ((const f4*)W1)[idx];
    float m = fmaxf(fmaxf(v.x, v.y), fmaxf(v.z, v.w));
    m = fmaxf(m, 0.f);
    unsigned u = __float_as_uint(m);
    #pragma unroll
    for (int o = 1; o < 64; o <<= 1) {
      unsigned w = __shfl_xor(u, o);
      u = w > u ? w : u;
    }
    if ((t & 63) == 0) atomicMax((unsigned*)(ws + SCAL_OFF + 1), u);
  }
}

// load 16 elements x 192 k of x into regs (12 f4/lane), coalesced 64B chunks.
// lane -> row = lane>>2, col = (lane&3)+4k; k<8 is spk (col<32), k>=8 is crd.
#define ALOAD(dst, ce0_)                                                     \
  {                                                                          \
    const f4* sp4_ = (const f4*)spk + ((size_t)(ce0_) + ar) * 32;            \
    const f4* cr4_ = (const f4*)crd + ((size_t)(ce0_) + ar) * 16;            \
    _Pragma("unroll")                                                        \
    for (int k = 0; k < 12; ++k) {                                           \
      const int col = ap + 4*k;                                              \
      const f4* src_ = (k < 8) ? (sp4_ + col) : (cr4_ + (col - 32));         \
      dst[k] = __builtin_nontemporal_load(src_);                             \
    }                                                                        \
  }

__global__ __launch_bounds__(BLOCK, 2)
void snn_kernel(const float* __restrict__ spk,
                const float* __restrict__ crd,
                const float* __restrict__ W0,
                const float* __restrict__ b0,
                const float* __restrict__ b1,
                const float* __restrict__ bout,
                const float* __restrict__ ws,
                float* __restrict__ out) {
  // R5: barrier-free autonomous waves.
  //   * W0b staged ONCE into LDS (rows padded to 200 us -> bank-uniform
  //     ds_read_b128), one barrier total.
  //   * each wave owns 64 elements (4 chunks of 16) x ALL 256 neurons:
  //     spike counts are within-wave (quad shfl + one ballot) -> no
  //     cross-wave reduction, no per-tile barriers, waves free-run.
  //   * chunk m+1's 12 global loads issued under chunk m's MFMA phase;
  //     stores stream continuously -> store BW is the only throttle.
  __shared__ unsigned short w0s[256*200];          // 102400 B
  __shared__ unsigned short xs[BLOCK/64][16*200];  //  51200 B (per-wave slice)

  const int tid  = threadIdx.x;
  const int lane = tid & 63;
  const int wv   = tid >> 6;            // wave 0..7
  const int quad = lane >> 4;
  const int l15  = lane & 15;
  const int i4   = lane * 4;
  const int ar   = lane >> 2;           // staging row 0..15
  const int ap   = lane & 3;            // staging col phase
  const int we0  = blockIdx.x * (BLOCK/64*64) + wv * 64;  // wave's 64 elements

  // chunk 0 staging loads in flight first...
  f4 stg[12];
  ALOAD(stg, we0)

  // ...W0b global->LDS under them (coalesced uint4, rows padded 192->200)
  {
    const uint4* wsrc = (const uint4*)ws;          // 6144 x 16B
    for (int i = tid; i < 6144; i += BLOCK) {
      int row = i / 24, c = i - row*24;            // 24 uint4 per row
      *(uint4*)&w0s[row*200 + c*8] = wsrc[i];
    }
  }

  // per-lane constants (independent loads, overlap the above)
  float b0n[16];
  #pragma unroll
  for (int n = 0; n < 16; ++n) b0n[n] = b0[n*16 + l15];
  const float b1mx = ws[SCAL_OFF];
  const float w1pm = ws[SCAL_OFF + 1];
  const float bc = bout[SPIKE_DIM + lane];

  __syncthreads();                      // the ONLY barrier
  unsigned short* myxs = &xs[wv][0];

  for (int m = 0; m < 4; ++m) {
    const int ce0 = we0 + m*16;

    // publish staged x to own slice (in-wave DS ordering; no barrier)
    #pragma unroll
    for (int k = 0; k < 12; ++k) {
      us4 h;
      h.x = f2bf(stg[k].x); h.y = f2bf(stg[k].y);
      h.z = f2bf(stg[k].z); h.w = f2bf(stg[k].w);
      *(us4*)&myxs[ar*200 + (ap + 4*k)*4] = h;
    }
    if (m < 3) ALOAD(stg, ce0 + 16)     // issue-early: hides under MFMAs

    // A fragments for this chunk (rows = elements, read once)
    bf8 afr[6];
    #pragma unroll
    for (int kc = 0; kc < 6; ++kc)
      afr[kc] = *(const bf8*)&myxs[l15*200 + kc*32 + quad*8];

    // ---- 16 n-tiles x (6 ds_read B + 6 MFMA); counts in-register ----
    // C/D layout: col(neuron)=l15, row(element)=quad*4+reg.
    // Rigor: exact-spiking layer-0 neuron has exact c0 >= 0.96; bf16-input
    // MFMA error <= ~0.05 (f32 accumulate) -> acc+b0 >= 0.90 counts it
    // (strict superset). 16-bit packed fields: max 256 can't wrap.
    unsigned c01 = 0, c23 = 0;
    #pragma unroll
    for (int n = 0; n < 16; ++n) {
      f4 acc; acc.x = acc.y = acc.z = acc.w = 0.f;
      #pragma unroll
      for (int kc = 0; kc < 6; ++kc) {
        bf8 b = *(const bf8*)&w0s[(n*16 + l15)*200 + kc*32 + quad*8];
        acc = __builtin_amdgcn_mfma_f32_16x16x32_bf16(afr[kc], b, acc, 0, 0, 0);
      }
      const float bn = b0n[n];
      c01 += (acc.x + bn >= 0.90f) ? 1u       : 0u;
      c01 += (acc.y + bn >= 0.90f) ? 0x10000u : 0u;
      c23 += (acc.z + bn >= 0.90f) ? 1u       : 0u;
      c23 += (acc.w + bn >= 0.90f) ? 0x10000u : 0u;
    }
    // quad-local reduce over the 16 neuron-columns
    c01 += __shfl_xor(c01, 1, 16); c23 += __shfl_xor(c23, 1, 16);
    c01 += __shfl_xor(c01, 2, 16); c23 += __shfl_xor(c23, 2, 16);
    c01 += __shfl_xor(c01, 4, 16); c23 += __shfl_xor(c23, 4, 16);
    c01 += __shfl_xor(c01, 8, 16); c23 += __shfl_xor(c23, 8, 16);

    // lane j<16 fetches element j's total; one ballot -> wave-uniform mask
    unsigned a01 = __shfl(c01, (lane & 12) << 2);
    unsigned a23 = __shfl(c23, (lane & 12) << 2);
    unsigned cw  = (lane & 2) ? a23 : a01;
    unsigned nspk = (cw >> ((lane & 1) << 4)) & 0xFFFFu;
    // Screen: c1_i(t) <= max(b1,0) + nspk*max(W1+,0) < 0.97 => s1 == 0 =>
    // outputs (0, b_out) EXACT. Garbage scalars fail closed (exact path).
    bool fast = (lane < 16) && (b1mx + w1pm * (float)nspk < 0.97f);
    unsigned mask16 = (unsigned)__ballot(fast) & 0xFFFFu;

    // bulk fast-path stores (fire-and-forget; backpressure = BW floor)
    #pragma unroll
    for (int ee = 0; ee < 16; ++ee) {
      if (mask16 & (1u << ee)) {
        const size_t e = (size_t)ce0 + ee;
        f4 z; z.x = z.y = z.z = z.w = 0.f;
        __builtin_nontemporal_store(z, (f4*)&out[e*HID + i4]);
        __builtin_nontemporal_store(bc,
            &out[(size_t)BATCH_N*HID + e*COORD_DIM + lane]);
      }
    }

    // rare (~P 3e-5/element): verbatim exact path
    if (__builtin_expect(mask16 != 0xFFFFu, 0)) {
      const float* W1T = ws + W1T_OFF;
      const float* WoT = ws + WOT_OFF;
      f4 b0v = *(const f4*)&b0[i4];
      f4 b1v = *(const f4*)&b1[i4];
      for (int ee = 0; ee < 16; ++ee) {
        if (mask16 & (1u << ee)) continue;
        const size_t e = (size_t)ce0 + ee;

        // ---- exact c0 recompute from global x, W0 (serial FMA, j ascending)
        float cx = 0.f, cy = 0.f, cz = 0.f, cw_ = 0.f;
        const float* q0 = W0 + (size_t)(i4+0)*IN_DIM;
        const float* q1 = W0 + (size_t)(i4+1)*IN_DIM;
        const float* q2 = W0 + (size_t)(i4+2)*IN_DIM;
        const float* q3 = W0 + (size_t)(i4+3)*IN_DIM;
        const float* xs_ = spk + e*SPIKE_DIM;
        const float* xc_ = crd + e*COORD_DIM;
        for (int j = 0; j < SPIKE_DIM; ++j) {
          float xj = xs_[j];
          cx = fmaf(xj, q0[j], cx); cy = fmaf(xj, q1[j], cy);
          cz = fmaf(xj, q2[j], cz); cw_ = fmaf(xj, q3[j], cw_);
        }
        for (int j = 0; j < COORD_DIM; ++j) {
          float xj = xc_[j];
          cx = fmaf(xj, q0[SPIKE_DIM+j], cx); cy = fmaf(xj, q1[SPIKE_DIM+j], cy);
          cz = fmaf(xj, q2[SPIKE_DIM+j], cz); cw_ = fmaf(xj, q3[SPIKE_DIM+j], cw_);
        }
        const float c0x = cx + b0v.x, c0y = cy + b0v.y;
        const float c0z = cz + b0v.z, c0w = cw_ + b0v.w;

        // ---- honest 25-step simulation (exact)
        float v0x=0.f, v0y=0.f, v0z=0.f, v0w=0.f;
        float v1x=0.f, v1y=0.f, v1z=0.f, v1w=0.f;
        float s1x=0.f, s1y=0.f, s1z=0.f, s1w=0.f;
        unsigned long long mm;

        for (int t = 0; t < STEPS; ++t) {
          bool sp;
          unsigned long long m0, m1, m2, m3;
          v0x = __fmul_rn(0.7f, v0x) + __fmul_rn(0.3f, c0x);
          sp = (v0x >= 1.0f); m0 = __ballot(sp); if (sp) v0x = 0.f;
          v0y = __fmul_rn(0.7f, v0y) + __fmul_rn(0.3f, c0y);
          sp = (v0y >= 1.0f); m1 = __ballot(sp); if (sp) v0y = 0.f;
          v0z = __fmul_rn(0.7f, v0z) + __fmul_rn(0.3f, c0z);
          sp = (v0z >= 1.0f); m2 = __ballot(sp); if (sp) v0z = 0.f;
          v0w = __fmul_rn(0.7f, v0w) + __fmul_rn(0.3f, c0w);
          sp = (v0w >= 1.0f); m3 = __ballot(sp); if (sp) v0w = 0.f;

          float c1x = b1v.x, c1y = b1v.y, c1z = b1v.z, c1w = b1v.w;
          f4 wcur; wcur.x = wcur.y = wcur.z = wcur.w = 0.f;
          int have = 0;
          #define PROCQ(MASK, Q)                                                  \
            mm = (MASK);                                                          \
            while (mm) {                                                          \
              int l = __builtin_ctzll(mm); mm &= mm - 1;                          \
              f4 wn = *(const f4*)&W1T[(l*4 + (Q))*HID + i4];                     \
              if (have) { c1x += wcur.x; c1y += wcur.y; c1z += wcur.z; c1w += wcur.w; } \
              wcur = wn; have = 1;                                                \
            }
          PROCQ(m0, 0)
          PROCQ(m1, 1)
          PROCQ(m2, 2)
          PROCQ(m3, 3)
          #undef PROCQ
          if (have) { c1x += wcur.x; c1y += wcur.y; c1z += wcur.z; c1w += wcur.w; }

          v1x = __fmul_rn(0.7f, v1x) + __fmul_rn(0.3f, c1x);
          sp = (v1x >= 1.0f); s1x = sp ? 1.f : 0.f; if (sp) v1x = 0.f;
          v1y = __fmul_rn(0.7f, v1y) + __fmul_rn(0.3f, c1y);
          sp = (v1y >= 1.0f); s1y = sp ? 1.f : 0.f; if (sp) v1y = 0.f;
          v1z = __fmul_rn(0.7f, v1z) + __fmul_rn(0.3f, c1z);
          sp = (v1z >= 1.0f); s1z = sp ? 1.f : 0.f; if (sp) v1z = 0.f;
          v1w = __fmul_rn(0.7f, v1w) + __fmul_rn(0.3f, c1w);
          sp = (v1w >= 1.0f); s1w = sp ? 1.f : 0.f; if (sp) v1w = 0.f;
        }

        f4 res; res.x = s1x; res.y = s1y; res.z = s1z; res.w = s1w;
        __builtin_nontemporal_store(res, (f4*)&out[e*HID + i4]);

        unsigned long long f0 = __ballot(s1x > 0.5f);
        unsigned long long f1 = __ballot(s1y > 0.5f);
        unsigned long long f2 = __ballot(s1z > 0.5f);
        unsigned long long f3 = __ballot(s1w > 0.5f);
        float cacc = bc;
        #define CPROCQ(MASK, Q)                                 \
          mm = (MASK);                                          \
          while (mm) {                                          \
            int l = __builtin_ctzll(mm); mm &= mm - 1;          \
            cacc += WoT[(l*4 + (Q))*COORD_DIM + lane];          \
          }
        CPROCQ(f0, 0)
        CPROCQ(f1, 1)
        CPROCQ(f2, 2)
        CPROCQ(f3, 3)
        #undef CPROCQ
        __builtin_nontemporal_store(cacc,
            &out[(size_t)BATCH_N*HID + e*COORD_DIM + lane]);
      }
    }
  }
}

extern "C" void kernel_launch(void* const* d_in, const int* in_sizes, int n_in,
                              void* d_out, int out_size, void* d_ws, size_t ws_size,
                              hipStream_t stream) {
  (void)in_sizes; (void)n_in; (void)out_size; (void)ws_size;
  const float* spk = (const float*)d_in[0];
  const float* crd = (const float*)d_in[1];
  const float* W0  = (const float*)d_in[2];
  const float* b0  = (const float*)d_in[3];
  const float* W1  = (const float*)d_in[4];
  const float* b1  = (const float*)d_in[5];
  const float* Wo  = (const float*)d_in[6];
  const float* bo  = (const float*)d_in[7];
  float* ws  = (float*)d_ws;
  float* out = (float*)d_out;

  hipMemsetAsync(ws + SCAL_OFF, 0, 8, stream);   // seed for atomicMax
  hipLaunchKernelGGL(prep_kernel, dim3(513), dim3(256), 0, stream, W0, W1, Wo, b1, ws);
  hipLaunchKernelGGL(snn_kernel, dim3(BATCH_N/(BLOCK/64*64)), dim3(BLOCK), 0, stream,
                     spk, crd, W0, b0, b1, bo, ws, out);
}

// Round 6
// 342.988 us; speedup vs baseline: 1.2961x; 1.2961x over previous
//
#include <hip/hip_runtime.h>
#include <stdint.h>

#define BATCH_N   131072
#define HID       256
#define SPIKE_DIM 128
#define COORD_DIM 64
#define IN_DIM    192
#define STEPS     25
#define TILE      64
#define BLOCK     512

typedef float f4  __attribute__((ext_vector_type(4)));
typedef short bf8 __attribute__((ext_vector_type(8)));
typedef unsigned short us4 __attribute__((ext_vector_type(4)));

// ws layout (floats):
//   W0b  [256][192] bf16   at 0            (24576 floats)
//   W1T  [256][256] fp32   at 24576
//   WoT  [256][64]  fp32   at 90112
//   scalars               at 106496: [0]=max(b1,0), [1]=max(W1+,0)
//   XB16 [8192 chunks][6 kc][64 lanes] x 16B bf16 A-frags at 106512
#define W1T_OFF  24576
#define WOT_OFF  90112
#define SCAL_OFF 106496
#define XB16_OFF 106512
#define XB16_NEED_BYTES ((size_t)XB16_OFF*4 + (size_t)BATCH_N*IN_DIM*2)

static __device__ __forceinline__ unsigned short f2bf(float f) {
  union { float f; unsigned u; } v; v.f = f;
  unsigned r = v.u + 0x7FFF + ((v.u >> 16) & 1);   // RNE
  return (unsigned short)(r >> 16);
}

__global__ __launch_bounds__(256)
void prep_kernel(const float* __restrict__ W0,
                 const float* __restrict__ W1,
                 const float* __restrict__ Wout,
                 const float* __restrict__ b1,
                 float* __restrict__ ws) {
  // Screen scalars via parallel wave-reduce + atomicMax on float bits
  // (values >=0 after fmaxf(.,0) => uint order == float order). ws[SCAL..]
  // zeroed by hipMemsetAsync before launch.
  const int t = threadIdx.x, b = blockIdx.x;
  if (b == 512) {
    unsigned u = __float_as_uint(fmaxf(b1[t], 0.f));
    #pragma unroll
    for (int o = 1; o < 64; o <<= 1) {
      unsigned v = __shfl_xor(u, o);
      u = v > u ? v : u;
    }
    if ((t & 63) == 0) atomicMax((unsigned*)(ws + SCAL_OFF), u);
    return;
  }
  int idx = b * 256 + t;
  if (idx < HID*IN_DIM) {               // W0b elementwise (row-major, k-contig)
    ((unsigned short*)ws)[idx] = f2bf(W0[idx]);
  }
  int i1 = idx - HID*IN_DIM;            // W1T[j][i] = W1[i][j]
  if (i1 >= 0 && i1 < HID*HID) {
    int j = i1 >> 8, i = i1 & 255;
    ws[W1T_OFF + i1] = W1[i*HID + j];
  }
  int i2 = idx - (HID*IN_DIM + HID*HID);// WoT[k][c] = Wout[128+c][k]
  if (i2 >= 0 && i2 < HID*COORD_DIM) {
    int k = i2 >> 6, c = i2 & 63;
    ws[WOT_OFF + i2] = Wout[(SPIKE_DIM + c)*HID + k];
  }
  if (b < 64) {                         // W1 max: 64 blocks cover 16384 f4
    f4 v = ((const f4*)W1)[idx];
    float m = fmaxf(fmaxf(v.x, v.y), fmaxf(v.z, v.w));
    m = fmaxf(m, 0.f);
    unsigned u = __float_as_uint(m);
    #pragma unroll
    for (int o = 1; o < 64; o <<= 1) {
      unsigned w = __shfl_xor(u, o);
      u = w > u ? w : u;
    }
    if ((t & 63) == 0) atomicMax((unsigned*)(ws + SCAL_OFF + 1), u);
  }
}

// x (f32, spk+crd) -> bf16, pre-tiled in exact MFMA A-fragment order:
//   frag(chunk c, kc, lane=quad*16+l15) = x[c*16+l15][kc*32+quad*8 .. +8]
//   stored at xb16[((c*6+kc)*64 + lane)*8], so snn reads wave-contiguous 1KB.
// Reads: per (c,kc) instruction pair, 16 rows x 128B segments (fully used).
__global__ __launch_bounds__(256)
void prep_x(const float* __restrict__ spk,
            const float* __restrict__ crd,
            float* __restrict__ ws) {
  const int tid  = threadIdx.x;
  const int w    = blockIdx.x * 4 + (tid >> 6);   // 0..49151
  const int lane = tid & 63;
  const int l15  = lane & 15;
  const int quad = lane >> 4;
  const int c    = w / 6, kc = w - c * 6;
  const float* src = (kc < 4)
      ? spk + (size_t)(c*16 + l15)*SPIKE_DIM + kc*32 + quad*8
      : crd + (size_t)(c*16 + l15)*COORD_DIM + (kc-4)*32 + quad*8;
  f4 a = *(const f4*)src;
  f4 b = *((const f4*)src + 1);
  uint4 o;
  o.x = (unsigned)f2bf(a.x) | ((unsigned)f2bf(a.y) << 16);
  o.y = (unsigned)f2bf(a.z) | ((unsigned)f2bf(a.w) << 16);
  o.z = (unsigned)f2bf(b.x) | ((unsigned)f2bf(b.y) << 16);
  o.w = (unsigned)f2bf(b.z) | ((unsigned)f2bf(b.w) << 16);
  unsigned short* xb16 = (unsigned short*)(ws + XB16_OFF);
  *(uint4*)&xb16[((size_t)w*64 + lane)*8] = o;    // 1KB contiguous per wave
}

// A-fragment load, tiled path: one dwordx4 per (m,kc), wave-contiguous 1KB.
#define LOAD_A1(dst, gm_)                                                    \
  { const size_t fb_ = ((size_t)(gm_)*6)*64 + lane;                          \
    _Pragma("unroll")                                                        \
    for (int kc_ = 0; kc_ < 6; ++kc_)                                        \
      dst[kc_] = *(const bf8*)&xb16[(fb_ + (size_t)kc_*64)*8]; }

// A-fragment load, no-workspace fallback: f32 direct + inline convert
// (identical numerics: same f2bf RNE).
#define LOAD_A0(dst, gm_)                                                    \
  { const int er_ = (gm_)*16 + l15;                                          \
    _Pragma("unroll")                                                        \
    for (int kc_ = 0; kc_ < 6; ++kc_) {                                      \
      const float* sA_ = (kc_ < 4)                                           \
        ? spk + (size_t)er_*SPIKE_DIM + kc_*32 + quad*8                      \
        : crd + (size_t)er_*COORD_DIM + (kc_-4)*32 + quad*8;                 \
      f4 x0_ = *(const f4*)sA_;                                              \
      f4 x1_ = *((const f4*)sA_ + 1);                                        \
      bf8 t_;                                                                \
      t_[0]=(short)f2bf(x0_.x); t_[1]=(short)f2bf(x0_.y);                    \
      t_[2]=(short)f2bf(x0_.z); t_[3]=(short)f2bf(x0_.w);                    \
      t_[4]=(short)f2bf(x1_.x); t_[5]=(short)f2bf(x1_.y);                    \
      t_[6]=(short)f2bf(x1_.z); t_[7]=(short)f2bf(x1_.w);                    \
      dst[kc_] = t_; } }

template<int TILED>
__global__ __launch_bounds__(BLOCK, 4)
void snn_kernel(const float* __restrict__ spk,
                const float* __restrict__ crd,
                const float* __restrict__ W0,
                const float* __restrict__ b0,
                const float* __restrict__ b1,
                const float* __restrict__ bout,
                const float* __restrict__ ws,
                float* __restrict__ out) {
  // R6: two-pass streaming. x arrives pre-converted & pre-tiled (prep_x),
  // so snn has NO x staging, NO LDS tile, NO stage barrier:
  //   per tile: {6 contiguous A-frag loads per m} -> 12 MFMA -> in-wave
  //   count pack -> LDS atomic combine -> 1 barrier -> screen -> stores.
  // B stays register-resident (R3's proven 12-frag scheme). LDS = 256 B.
  __shared__ unsigned cnt2[2*32];       // per-tile packed counts (16-bit fields)

  const int tid  = threadIdx.x;
  const int lane = tid & 63;
  const int wv   = tid >> 6;            // wave 0..7
  const int quad = lane >> 4;
  const int l15  = lane & 15;
  const int i4   = lane * 4;
  const int tileBase = blockIdx.x * 2;  // 2 tiles of 64 elements per block

  if (tid < 64) cnt2[tid] = 0;

  // per-block constants: 12 B-frags + biases + screen scalars (issued early,
  // all independent; ~400cy L2/L3, amortized over 128 elements)
  const unsigned short* W0b  = (const unsigned short*)ws;        // [256][192]
  const unsigned short* xb16 = (const unsigned short*)(ws + XB16_OFF);
  float b0n[2];
  b0n[0] = b0[wv*32 + l15];
  b0n[1] = b0[wv*32 + 16 + l15];
  bf8 bfr[2][6];
  #pragma unroll
  for (int n = 0; n < 2; ++n)
    #pragma unroll
    for (int kc = 0; kc < 6; ++kc)
      bfr[n][kc] = *(const bf8*)&W0b[(size_t)(wv*32 + n*16 + l15)*IN_DIM
                                     + kc*32 + quad*8];
  const float b1mx = ws[SCAL_OFF];
  const float w1pm = ws[SCAL_OFF + 1];
  const float bc = bout[SPIKE_DIM + lane];
  const int eb = wv * 8;

  __syncthreads();                      // publish cnt2 init (cheap: only init
                                        // + load-issues precede it)
  #pragma unroll
  for (int s = 0; s < 2; ++s) {
    unsigned* cw = &cnt2[s * 32];
    const int e0s = (tileBase + s) * TILE;

    // ---- MFMA per element-subtile m; counts straight from accumulators.
    // C/D layout: col(neuron)=l15, row(element)=m*16+quad*4+reg.
    // Rigor: exact-spiking layer-0 neuron has exact c0 >= 0.96; bf16-input
    // MFMA error <= ~0.05 (f32 accumulate) -> acc+b0 >= 0.90 counts it
    // (strict superset). 16-bit packed fields: max 256 can't wrap.
    #pragma unroll
    for (int m = 0; m < 4; ++m) {
      const int gm = (tileBase + s)*4 + m;    // global 16-element chunk
      bf8 afr[6];
      if (TILED) { LOAD_A1(afr, gm) } else { LOAD_A0(afr, gm) }
      f4 ac0, ac1;
      ac0.x = ac0.y = ac0.z = ac0.w = 0.f;
      ac1.x = ac1.y = ac1.z = ac1.w = 0.f;
      #pragma unroll
      for (int kc = 0; kc < 6; ++kc) {
        ac0 = __builtin_amdgcn_mfma_f32_16x16x32_bf16(afr[kc], bfr[0][kc], ac0, 0, 0, 0);
        ac1 = __builtin_amdgcn_mfma_f32_16x16x32_bf16(afr[kc], bfr[1][kc], ac1, 0, 0, 0);
      }
      unsigned lo = 0, hi = 0;
      lo += (ac0.x + b0n[0] >= 0.90f) ? 1u       : 0u;
      lo += (ac1.x + b0n[1] >= 0.90f) ? 1u       : 0u;
      lo += (ac0.y + b0n[0] >= 0.90f) ? 0x10000u : 0u;
      lo += (ac1.y + b0n[1] >= 0.90f) ? 0x10000u : 0u;
      hi += (ac0.z + b0n[0] >= 0.90f) ? 1u       : 0u;
      hi += (ac1.z + b0n[1] >= 0.90f) ? 1u       : 0u;
      hi += (ac0.w + b0n[0] >= 0.90f) ? 0x10000u : 0u;
      hi += (ac1.w + b0n[1] >= 0.90f) ? 0x10000u : 0u;
      lo += __shfl_xor(lo, 1, 16); hi += __shfl_xor(hi, 1, 16);
      lo += __shfl_xor(lo, 2, 16); hi += __shfl_xor(hi, 2, 16);
      lo += __shfl_xor(lo, 4, 16); hi += __shfl_xor(hi, 4, 16);
      lo += __shfl_xor(lo, 8, 16); hi += __shfl_xor(hi, 8, 16);
      if (l15 == 0) {                   // one leader per quad
        atomicAdd(&cw[(m*4 + quad)*2 + 0], lo);
        atomicAdd(&cw[(m*4 + quad)*2 + 1], hi);
      }
    }
    __syncthreads();                    // counts complete for tile s
                                        // (s=1 atomics hit disjoint slice)

    // ---- screen (no loads) -> bulk stores; rare exact fallback ----
    // c1_i(t) <= max(b1,0) + nspk*max(W1+,0) < 0.97 => s1 == 0 => outputs
    // (0, b_out) EXACT. Garbage scalars fail closed into the exact path.
    unsigned fastm = 0;
    #pragma unroll
    for (int ee = 0; ee < 8; ++ee) {
      const int el = eb + ee;
      unsigned w = cw[(el >> 2)*2 + ((el >> 1) & 1)];
      unsigned nspk = (w >> ((el & 1)*16)) & 0xFFFFu;
      if (b1mx + w1pm * (float)nspk < 0.97f) fastm |= (1u << ee);
    }

    #pragma unroll
    for (int ee = 0; ee < 8; ++ee) {
      if (fastm & (1u << ee)) {
        const int e = e0s + eb + ee;
        f4 z; z.x = z.y = z.z = z.w = 0.f;
        __builtin_nontemporal_store(z, (f4*)&out[(size_t)e*HID + i4]);
        __builtin_nontemporal_store(bc,
            &out[(size_t)BATCH_N*HID + (size_t)e*COORD_DIM + lane]);
      }
    }

    // rare (~P 3e-5/element): verbatim exact path
    if (__builtin_expect(fastm != 0xFFu, 0)) {
      const float* W1T = ws + W1T_OFF;
      const float* WoT = ws + WOT_OFF;
      f4 b0v = *(const f4*)&b0[i4];
      f4 b1v = *(const f4*)&b1[i4];
      for (int ee = 0; ee < 8; ++ee) {
        if (fastm & (1u << ee)) continue;
        const int e = e0s + eb + ee;

        // ---- exact c0 recompute from global x, W0 (serial FMA, j ascending)
        float cx = 0.f, cy = 0.f, cz = 0.f, cw_ = 0.f;
        const float* q0 = W0 + (size_t)(i4+0)*IN_DIM;
        const float* q1 = W0 + (size_t)(i4+1)*IN_DIM;
        const float* q2 = W0 + (size_t)(i4+2)*IN_DIM;
        const float* q3 = W0 + (size_t)(i4+3)*IN_DIM;
        const float* xs_ = spk + (size_t)e*SPIKE_DIM;
        const float* xc_ = crd + (size_t)e*COORD_DIM;
        for (int j = 0; j < SPIKE_DIM; ++j) {
          float xj = xs_[j];
          cx = fmaf(xj, q0[j], cx); cy = fmaf(xj, q1[j], cy);
          cz = fmaf(xj, q2[j], cz); cw_ = fmaf(xj, q3[j], cw_);
        }
        for (int j = 0; j < COORD_DIM; ++j) {
          float xj = xc_[j];
          cx = fmaf(xj, q0[SPIKE_DIM+j], cx); cy = fmaf(xj, q1[SPIKE_DIM+j], cy);
          cz = fmaf(xj, q2[SPIKE_DIM+j], cz); cw_ = fmaf(xj, q3[SPIKE_DIM+j], cw_);
        }
        const float c0x = cx + b0v.x, c0y = cy + b0v.y;
        const float c0z = cz + b0v.z, c0w = cw_ + b0v.w;

        // ---- honest 25-step simulation (exact)
        float v0x=0.f, v0y=0.f, v0z=0.f, v0w=0.f;
        float v1x=0.f, v1y=0.f, v1z=0.f, v1w=0.f;
        float s1x=0.f, s1y=0.f, s1z=0.f, s1w=0.f;
        unsigned long long mm;

        for (int t = 0; t < STEPS; ++t) {
          bool sp;
          unsigned long long m0, m1, m2, m3;
          v0x = __fmul_rn(0.7f, v0x) + __fmul_rn(0.3f, c0x);
          sp = (v0x >= 1.0f); m0 = __ballot(sp); if (sp) v0x = 0.f;
          v0y = __fmul_rn(0.7f, v0y) + __fmul_rn(0.3f, c0y);
          sp = (v0y >= 1.0f); m1 = __ballot(sp); if (sp) v0y = 0.f;
          v0z = __fmul_rn(0.7f, v0z) + __fmul_rn(0.3f, c0z);
          sp = (v0z >= 1.0f); m2 = __ballot(sp); if (sp) v0z = 0.f;
          v0w = __fmul_rn(0.7f, v0w) + __fmul_rn(0.3f, c0w);
          sp = (v0w >= 1.0f); m3 = __ballot(sp); if (sp) v0w = 0.f;

          float c1x = b1v.x, c1y = b1v.y, c1z = b1v.z, c1w = b1v.w;
          f4 wcur; wcur.x = wcur.y = wcur.z = wcur.w = 0.f;
          int have = 0;
          #define PROCQ(MASK, Q)                                                  \
            mm = (MASK);                                                          \
            while (mm) {                                                          \
              int l = __builtin_ctzll(mm); mm &= mm - 1;                          \
              f4 wn = *(const f4*)&W1T[(l*4 + (Q))*HID + i4];                     \
              if (have) { c1x += wcur.x; c1y += wcur.y; c1z += wcur.z; c1w += wcur.w; } \
              wcur = wn; have = 1;                                                \
            }
          PROCQ(m0, 0)
          PROCQ(m1, 1)
          PROCQ(m2, 2)
          PROCQ(m3, 3)
          #undef PROCQ
          if (have) { c1x += wcur.x; c1y += wcur.y; c1z += wcur.z; c1w += wcur.w; }

          v1x = __fmul_rn(0.7f, v1x) + __fmul_rn(0.3f, c1x);
          sp = (v1x >= 1.0f); s1x = sp ? 1.f : 0.f; if (sp) v1x = 0.f;
          v1y = __fmul_rn(0.7f, v1y) + __fmul_rn(0.3f, c1y);
          sp = (v1y >= 1.0f); s1y = sp ? 1.f : 0.f; if (sp) v1y = 0.f;
          v1z = __fmul_rn(0.7f, v1z) + __fmul_rn(0.3f, c1z);
          sp = (v1z >= 1.0f); s1z = sp ? 1.f : 0.f; if (sp) v1z = 0.f;
          v1w = __fmul_rn(0.7f, v1w) + __fmul_rn(0.3f, c1w);
          sp = (v1w >= 1.0f); s1w = sp ? 1.f : 0.f; if (sp) v1w = 0.f;
        }

        f4 res; res.x = s1x; res.y = s1y; res.z = s1z; res.w = s1w;
        __builtin_nontemporal_store(res, (f4*)&out[(size_t)e*HID + i4]);

        unsigned long long f0 = __ballot(s1x > 0.5f);
        unsigned long long f1 = __ballot(s1y > 0.5f);
        unsigned long long f2 = __ballot(s1z > 0.5f);
        unsigned long long f3 = __ballot(s1w > 0.5f);
        float cacc = bc;
        #define CPROCQ(MASK, Q)                                 \
          mm = (MASK);                                          \
          while (mm) {                                          \
            int l = __builtin_ctzll(mm); mm &= mm - 1;          \
            cacc += WoT[(l*4 + (Q))*COORD_DIM + lane];          \
          }
        CPROCQ(f0, 0)
        CPROCQ(f1, 1)
        CPROCQ(f2, 2)
        CPROCQ(f3, 3)
        #undef CPROCQ
        __builtin_nontemporal_store(cacc,
            &out[(size_t)BATCH_N*HID + (size_t)e*COORD_DIM + lane]);
      }
    }
  }
}

extern "C" void kernel_launch(void* const* d_in, const int* in_sizes, int n_in,
                              void* d_out, int out_size, void* d_ws, size_t ws_size,
                              hipStream_t stream) {
  (void)in_sizes; (void)n_in; (void)out_size;
  const float* spk = (const float*)d_in[0];
  const float* crd = (const float*)d_in[1];
  const float* W0  = (const float*)d_in[2];
  const float* b0  = (const float*)d_in[3];
  const float* W1  = (const float*)d_in[4];
  const float* b1  = (const float*)d_in[5];
  const float* Wo  = (const float*)d_in[6];
  const float* bo  = (const float*)d_in[7];
  float* ws  = (float*)d_ws;
  float* out = (float*)d_out;

  hipMemsetAsync(ws + SCAL_OFF, 0, 8, stream);   // seed for atomicMax
  hipLaunchKernelGGL(prep_kernel, dim3(513), dim3(256), 0, stream, W0, W1, Wo, b1, ws);
  if (ws_size >= XB16_NEED_BYTES) {
    hipLaunchKernelGGL(prep_x, dim3(BATCH_N/16*6/4), dim3(256), 0, stream,
                       spk, crd, ws);
    hipLaunchKernelGGL((snn_kernel<1>), dim3(BATCH_N/(TILE*2)), dim3(BLOCK), 0,
                       stream, spk, crd, W0, b0, b1, bo, ws, out);
  } else {
    hipLaunchKernelGGL((snn_kernel<0>), dim3(BATCH_N/(TILE*2)), dim3(BLOCK), 0,
                       stream, spk, crd, W0, b0, b1, bo, ws, out);
  }
}